// Round 1
// baseline (6000.028 us; speedup 1.0000x reference)
//
#include <hip/hip_runtime.h>
#include <math.h>

#define T_SEQ 2048
#define HID   4096
#define NH    32
#define NKV   8
#define HD    128
#define QCOLS (NH*HD)   // 4096
#define KCOLS (NKV*HD)  // 1024

// ---------------- RoPE cos/sin table (llama3 scaling), f64 math ----------------
__global__ void rope_table(float* __restrict__ cosT, float* __restrict__ sinT) {
    int idx = blockIdx.x * blockDim.x + threadIdx.x;   // t*64 + i
    if (idx >= T_SEQ * 64) return;
    int t = idx >> 6, i = idx & 63;
    double inv = pow(500000.0, -(double)(2 * i) / 128.0);
    double wavelen = 6.283185307179586 / inv;
    const double lowwl = 8192.0, highwl = 2048.0;
    double scaled;
    if (wavelen > lowwl) {
        scaled = inv / 8.0;
    } else if (wavelen >= highwl) {
        double smooth = (8192.0 / wavelen - 1.0) / 3.0;
        scaled = (1.0 - smooth) * inv / 8.0 + smooth * inv;
    } else {
        scaled = inv;
    }
    // emulate reference fp32 rounding: inv->f32, pos*inv in f32, then cos/sin
    float invf = (float)scaled;
    float phase = (float)t * invf;
    cosT[idx] = (float)cos((double)phase);
    sinT[idx] = (float)sin((double)phase);
}

// ---------------- fp32 tiled GEMM: C[M,N] = A[M,K] @ B[K,N] ----------------
// M,N multiples of 64; K multiple of 16.
__global__ __launch_bounds__(256) void gemm_f32(const float* __restrict__ A,
                                                const float* __restrict__ B,
                                                float* __restrict__ C,
                                                int M, int N, int K) {
    __shared__ float As[16][68];  // [k][m], +4 pad kills store conflicts
    __shared__ float Bs[16][64];  // [k][n]
    const int tid = threadIdx.x;
    const int tx = tid & 15, ty = tid >> 4;
    const int m0 = blockIdx.y * 64, n0 = blockIdx.x * 64;
    float acc[4][4] = {};
    for (int k0 = 0; k0 < K; k0 += 16) {
        {   // A tile: 64 rows x 16 k, one float4/thread, store transposed
            int m = tid >> 2, k4 = (tid & 3) * 4;
            const float4 av = *(const float4*)(A + (size_t)(m0 + m) * K + k0 + k4);
            As[k4 + 0][m] = av.x; As[k4 + 1][m] = av.y;
            As[k4 + 2][m] = av.z; As[k4 + 3][m] = av.w;
        }
        {   // B tile: 16 k x 64 n, one float4/thread
            int k = tid >> 4, n4 = (tid & 15) * 4;
            *(float4*)(&Bs[k][n4]) = *(const float4*)(B + (size_t)(k0 + k) * N + n0 + n4);
        }
        __syncthreads();
#pragma unroll
        for (int k = 0; k < 16; ++k) {
            float a[4], b[4];
#pragma unroll
            for (int i = 0; i < 4; ++i) a[i] = As[k][ty * 4 + i];
#pragma unroll
            for (int j = 0; j < 4; ++j) b[j] = Bs[k][tx * 4 + j];
#pragma unroll
            for (int i = 0; i < 4; ++i)
#pragma unroll
                for (int j = 0; j < 4; ++j)
                    acc[i][j] = fmaf(a[i], b[j], acc[i][j]);
        }
        __syncthreads();
    }
#pragma unroll
    for (int i = 0; i < 4; ++i) {
        float4 v4 = make_float4(acc[i][0], acc[i][1], acc[i][2], acc[i][3]);
        *(float4*)(C + (size_t)(m0 + ty * 4 + i) * N + n0 + tx * 4) = v4;
    }
}

// ---------------- RoPE apply (in place), one wave per (t, head) row ----------------
__global__ void rope_apply(float* __restrict__ data, const float* __restrict__ cosT,
                           const float* __restrict__ sinT, int nheads) {
    int idx = blockIdx.x * blockDim.x + threadIdx.x;
    int lane = idx & 63;
    int row = idx >> 6;  // t*nheads + h
    if (row >= T_SEQ * nheads) return;
    int t = row / nheads, h = row % nheads;
    float* p = data + (size_t)t * (nheads * HD) + h * HD;
    float c = cosT[t * 64 + lane], s = sinT[t * 64 + lane];
    float x1 = p[lane], x2 = p[lane + 64];
    p[lane]      = x1 * c - x2 * s;
    p[lane + 64] = x2 * c + x1 * s;
}

// ---------------- causal GQA flash attention, fp32 ----------------
// grid: (T/4, NH); block 256 = 4 waves; wave w -> query row blockIdx.x*4+w.
__global__ __launch_bounds__(256) void attn_kernel(const float* __restrict__ q,
                                                   const float* __restrict__ k,
                                                   const float* __restrict__ v,
                                                   float* __restrict__ out) {
    __shared__ float Ks[64][128];  // K chunk, float4-XOR-swizzled rows
    __shared__ float Qs[4][128];   // per-wave q row
    const int tid = threadIdx.x;
    const int w = tid >> 6, lane = tid & 63;
    const int h = blockIdx.y;
    const int g = h >> 2;                 // kv head (rep = 4)
    const int t = blockIdx.x * 4 + w;     // query row of this wave
    const int tmax = blockIdx.x * 4 + 3;

    Qs[w][lane]      = q[(size_t)t * QCOLS + h * HD + lane];
    Qs[w][lane + 64] = q[(size_t)t * QCOLS + h * HD + lane + 64];

    float m = -INFINITY, l = 0.f;
    float acc0 = 0.f, acc1 = 0.f;  // d = 2*lane, 2*lane+1

    const int nchunks = tmax / 64 + 1;
    for (int c = 0; c < nchunks; ++c) {
        const int s0 = c * 64;
        __syncthreads();
        // stage K chunk: 64 rows x 128 floats = 2048 float4, 8 per thread
#pragma unroll
        for (int i = 0; i < 8; ++i) {
            int f4 = i * 256 + tid;
            int r = f4 >> 5, d4 = f4 & 31;
            const float4 kf = *(const float4*)(k + (size_t)(s0 + r) * KCOLS + g * HD + d4 * 4);
            int sw = d4 ^ (r & 31);
            *(float4*)(&Ks[r][sw * 4]) = kf;
        }
        __syncthreads();
        if (s0 > t) continue;  // no barriers below: safe

        // --- scores: lane j handles key s0+lane ---
        float x = 0.f;
#pragma unroll
        for (int d4 = 0; d4 < 32; ++d4) {
            int sw = d4 ^ (lane & 31);
            float4 kf = *(const float4*)(&Ks[lane][sw * 4]);
            float4 qf = *(const float4*)(&Qs[w][d4 * 4]);
            x = fmaf(kf.x, qf.x, x); x = fmaf(kf.y, qf.y, x);
            x = fmaf(kf.z, qf.z, x); x = fmaf(kf.w, qf.w, x);
        }
        x *= 0.08838834764831845f;                 // 1/sqrt(128)
        if (s0 + lane > t) x = -INFINITY;          // causal mask

        // --- online softmax ---
        float cmax = x;
#pragma unroll
        for (int off = 1; off < 64; off <<= 1) cmax = fmaxf(cmax, __shfl_xor(cmax, off));
        float mnew = fmaxf(m, cmax);
        float scale = expf(m - mnew);
        float p = expf(x - mnew);
        float psum = p;
#pragma unroll
        for (int off = 1; off < 64; off <<= 1) psum += __shfl_xor(psum, off);
        l = l * scale + psum;
        acc0 *= scale; acc1 *= scale;
        m = mnew;

        // --- PV: V read straight from global (coalesced, L2-resident) ---
        const int jmax = min(63, t - s0);
        const float* vrow = v + (size_t)s0 * KCOLS + g * HD + 2 * lane;
        for (int j = 0; j <= jmax; ++j) {
            float pj = __shfl(p, j);
            float2 vv = *(const float2*)(vrow + (size_t)j * KCOLS);
            acc0 = fmaf(pj, vv.x, acc0);
            acc1 = fmaf(pj, vv.y, acc1);
        }
    }

    float invl = 1.f / l;
    float2 o = make_float2(acc0 * invl, acc1 * invl);
    *(float2*)(out + (size_t)t * QCOLS + h * HD + 2 * lane) = o;
}

// ---------------- host launch ----------------
extern "C" void kernel_launch(void* const* d_in, const int* in_sizes, int n_in,
                              void* d_out, int out_size, void* d_ws, size_t ws_size,
                              hipStream_t stream) {
    const float* x  = (const float*)d_in[0];
    const float* wq = (const float*)d_in[1];
    const float* wk = (const float*)d_in[2];
    const float* wv = (const float*)d_in[3];
    const float* wo = (const float*)d_in[4];
    float* out = (float*)d_out;

    char* ws = (char*)d_ws;
    float* cosT = (float*)(ws);                          // 2048*64*4 = 512 KB
    float* sinT = (float*)(ws + 524288ULL);              // 512 KB
    float* qb   = (float*)(ws + 1048576ULL);             // 32 MB
    float* kb   = (float*)(ws + 34603008ULL);            // 8 MB
    float* vb   = (float*)(ws + 42991616ULL);            // 8 MB
    float* att  = (float*)(ws + 51380224ULL);            // 32 MB

    hipLaunchKernelGGL(rope_table, dim3((T_SEQ * 64 + 255) / 256), dim3(256), 0, stream,
                       cosT, sinT);

    dim3 gq(QCOLS / 64, T_SEQ / 64);
    dim3 gk(KCOLS / 64, T_SEQ / 64);
    hipLaunchKernelGGL(gemm_f32, gq, dim3(256), 0, stream, x, wq, qb, T_SEQ, QCOLS, HID);
    hipLaunchKernelGGL(gemm_f32, gk, dim3(256), 0, stream, x, wk, kb, T_SEQ, KCOLS, HID);
    hipLaunchKernelGGL(gemm_f32, gk, dim3(256), 0, stream, x, wv, vb, T_SEQ, KCOLS, HID);

    hipLaunchKernelGGL(rope_apply, dim3(T_SEQ * NH * 64 / 256), dim3(256), 0, stream,
                       qb, cosT, sinT, NH);
    hipLaunchKernelGGL(rope_apply, dim3(T_SEQ * NKV * 64 / 256), dim3(256), 0, stream,
                       kb, cosT, sinT, NKV);

    hipLaunchKernelGGL(attn_kernel, dim3(T_SEQ / 4, NH), dim3(256), 0, stream,
                       qb, kb, vb, att);

    hipLaunchKernelGGL(gemm_f32, gq, dim3(256), 0, stream, att, wo, out, T_SEQ, QCOLS, HID);
}

// Round 3
// 737.076 us; speedup vs baseline: 8.1403x; 8.1403x over previous
//
#include <hip/hip_runtime.h>
#include <math.h>

#define T_SEQ 2048
#define HID   4096
#define NH    32
#define NKV   8
#define HD    128
#define QCOLS (NH*HD)   // 4096
#define KCOLS (NKV*HD)  // 1024

typedef _Float16 f16;
typedef _Float16 f16x8 __attribute__((ext_vector_type(8)));
typedef _Float16 f16x4 __attribute__((ext_vector_type(4)));
typedef float f32x4 __attribute__((ext_vector_type(4)));

#define GLDS(g, l) __builtin_amdgcn_global_load_lds( \
    (const __attribute__((address_space(1))) void*)(g), \
    (__attribute__((address_space(3))) void*)(l), 16, 0, 0)

// ---------------- RoPE cos/sin table (llama3 scaling), f64 math ----------------
__global__ void rope_table(float* __restrict__ cosT, float* __restrict__ sinT) {
    int idx = blockIdx.x * blockDim.x + threadIdx.x;   // t*64 + i
    if (idx >= T_SEQ * 64) return;
    int t = idx >> 6, i = idx & 63;
    double inv = pow(500000.0, -(double)(2 * i) / 128.0);
    double wavelen = 6.283185307179586 / inv;
    const double lowwl = 8192.0, highwl = 2048.0;
    double scaled;
    if (wavelen > lowwl) {
        scaled = inv / 8.0;
    } else if (wavelen >= highwl) {
        double smooth = (8192.0 / wavelen - 1.0) / 3.0;
        scaled = (1.0 - smooth) * inv / 8.0 + smooth * inv;
    } else {
        scaled = inv;
    }
    float invf = (float)scaled;
    float phase = (float)t * invf;
    cosT[idx] = (float)cos((double)phase);
    sinT[idx] = (float)sin((double)phase);
}

// ---------------- fp32 -> f16 convert (row-major copy) ----------------
__global__ void convert_f32_f16(const float* __restrict__ in, f16* __restrict__ out, int n8) {
    int i = blockIdx.x * blockDim.x + threadIdx.x;
    if (i >= n8) return;
    float4 a = *(const float4*)(in + (size_t)i * 8);
    float4 b = *(const float4*)(in + (size_t)i * 8 + 4);
    f16x8 v = {(f16)a.x, (f16)a.y, (f16)a.z, (f16)a.w, (f16)b.x, (f16)b.y, (f16)b.z, (f16)b.w};
    *(f16x8*)(out + (size_t)i * 8) = v;
}

// ---------------- fp32 [rows][ld] col-slice -> f16 [cols][R] transpose ----------------
// in: already offset to the first column of the slice; grid.x covers slice cols/64,
// grid.y covers R/64 rows. out has row stride R.
__global__ __launch_bounds__(256) void transpose_f32_to_f16(const float* __restrict__ in,
                                                            f16* __restrict__ out,
                                                            int R, int ld) {
    __shared__ f16 t[64][72];
    const int tid = threadIdx.x;
    const int r0 = blockIdx.y * 64, c0 = blockIdx.x * 64;
#pragma unroll
    for (int i = 0; i < 4; ++i) {
        int r = i * 16 + (tid >> 4), c4 = (tid & 15) * 4;
        float4 v = *(const float4*)(in + (size_t)(r0 + r) * ld + c0 + c4);
        t[r][c4 + 0] = (f16)v.x; t[r][c4 + 1] = (f16)v.y;
        t[r][c4 + 2] = (f16)v.z; t[r][c4 + 3] = (f16)v.w;
    }
    __syncthreads();
    int n = tid >> 2, j0 = (tid & 3) * 16;
    f16x8 a, b;
#pragma unroll
    for (int j = 0; j < 8; ++j) { a[j] = t[j0 + j][n]; b[j] = t[j0 + 8 + j][n]; }
    *(f16x8*)(out + (size_t)(c0 + n) * R + r0 + j0) = a;
    *(f16x8*)(out + (size_t)(c0 + n) * R + r0 + j0 + 8) = b;
}

// ---------------- f16 [R][C] -> f16 [C][R] transpose ----------------
__global__ __launch_bounds__(256) void transpose_f16(const f16* __restrict__ in,
                                                     f16* __restrict__ out,
                                                     int R, int C) {
    __shared__ f16 t[64][72];
    const int tid = threadIdx.x;
    const int r0 = blockIdx.y * 64, c0 = blockIdx.x * 64;
#pragma unroll
    for (int i = 0; i < 2; ++i) {
        int r = i * 32 + (tid >> 3), c8 = (tid & 7) * 8;
        f16x8 v = *(const f16x8*)(in + (size_t)(r0 + r) * C + c0 + c8);
#pragma unroll
        for (int j = 0; j < 8; ++j) t[r][c8 + j] = v[j];
    }
    __syncthreads();
    int n = tid >> 2, j0 = (tid & 3) * 16;
    f16x8 a, b;
#pragma unroll
    for (int j = 0; j < 8; ++j) { a[j] = t[j0 + j][n]; b[j] = t[j0 + 8 + j][n]; }
    *(f16x8*)(out + (size_t)(c0 + n) * R + r0 + j0) = a;
    *(f16x8*)(out + (size_t)(c0 + n) * R + r0 + j0 + 8) = b;
}

// ---------------- f16 MFMA GEMM: C[M, n-tile] = A[M,K] @ Bt[ntile,K]^T ----------------
// 128x128 tile, BK=32, 256 threads (4 waves, 2x2), m97-style 2-barrier loop.
// C pointer is pre-offset to the n-tile start; ldc is the full row stride.
template <typename OutT>
__global__ __launch_bounds__(256, 2) void gemm_f16(const f16* __restrict__ A,
                                                   const f16* __restrict__ Bt,
                                                   OutT* __restrict__ C,
                                                   int M, int ldc, int K) {
    __shared__ f16 As[128 * 32];
    __shared__ f16 Bs[128 * 32];
    const int tid = threadIdx.x;
    const int l = tid & 63;
    const int w = tid >> 6, wr = w >> 1, wc = w & 1;
    const int c16 = l & 15, g = l >> 4;
    const int m0 = blockIdx.y * 128, n0 = blockIdx.x * 128;

    f32x4 acc[4][4] = {};

    const f16* gA = A + (size_t)(m0 + (tid >> 2)) * K + (tid & 3) * 8;
    const f16* gB = Bt + (size_t)(n0 + (tid >> 2)) * K + (tid & 3) * 8;
    f16* lA = As + tid * 8;
    f16* lB = Bs + tid * 8;

    for (int k0 = 0; k0 < K; k0 += 32) {
        __syncthreads();
        GLDS(gA + k0, lA);
        GLDS(gA + (size_t)64 * K + k0, lA + 64 * 32);
        GLDS(gB + k0, lB);
        GLDS(gB + (size_t)64 * K + k0, lB + 64 * 32);
        __syncthreads();
        f16x8 af[4], bf[4];
#pragma unroll
        for (int mb = 0; mb < 4; ++mb)
            af[mb] = *(const f16x8*)(As + (wr * 64 + mb * 16 + c16) * 32 + g * 8);
#pragma unroll
        for (int nb = 0; nb < 4; ++nb)
            bf[nb] = *(const f16x8*)(Bs + (wc * 64 + nb * 16 + c16) * 32 + g * 8);
#pragma unroll
        for (int mb = 0; mb < 4; ++mb)
#pragma unroll
            for (int nb = 0; nb < 4; ++nb)
                acc[mb][nb] = __builtin_amdgcn_mfma_f32_16x16x32_f16(af[mb], bf[nb], acc[mb][nb], 0, 0, 0);
    }
#pragma unroll
    for (int mb = 0; mb < 4; ++mb)
#pragma unroll
        for (int nb = 0; nb < 4; ++nb)
#pragma unroll
            for (int r = 0; r < 4; ++r) {
                size_t row = m0 + wr * 64 + mb * 16 + g * 4 + r;
                C[row * ldc + n0 + wc * 64 + nb * 16 + c16] = (OutT)acc[mb][nb][r];
            }
}

// ---------------- RoPE apply in place on f16 ----------------
__global__ void rope_apply_f16(f16* __restrict__ data, const float* __restrict__ cosT,
                               const float* __restrict__ sinT, int nheads) {
    int idx = blockIdx.x * blockDim.x + threadIdx.x;
    int lane = idx & 63;
    int row = idx >> 6;
    if (row >= T_SEQ * nheads) return;
    int t = row / nheads, h = row % nheads;
    f16* p = data + (size_t)t * (nheads * HD) + h * HD;
    float c = cosT[t * 64 + lane], s = sinT[t * 64 + lane];
    float x1 = (float)p[lane], x2 = (float)p[lane + 64];
    p[lane]      = (f16)(x1 * c - x2 * s);
    p[lane + 64] = (f16)(x2 * c + x1 * s);
}

// ---------------- MFMA flash attention (swapped operands) ----------------
// grid (T/64, NH), 256 threads = 4 waves; wave w owns q rows qt*64+w*16..+15.
// S^T = K @ Q^T  (lane col = q), softmax state is per-lane scalar.
// O^T = Vt @ P^T, P routed through per-wave padded LDS.
__global__ __launch_bounds__(256, 2) void attn_f16(const f16* __restrict__ q,
                                                   const f16* __restrict__ k,
                                                   const f16* __restrict__ vt,
                                                   f16* __restrict__ outh) {
    __shared__ f16 Ks[64 * 128];   // rows of 256 B, XOR-swizzled
    __shared__ f16 Vs[128 * 64];   // Vt rows of 128 B, XOR-swizzled
    __shared__ f16 Ps[4][16 * 72]; // per-wave P, row stride 72 f16
    const int tid = threadIdx.x;
    const int l = tid & 63, w = tid >> 6;
    const int c16 = l & 15, g = l >> 4;
    const int qt = blockIdx.x, h = blockIdx.y, kvh = h >> 2;
    const int qrow = qt * 64 + w * 16 + c16;
    const float SCALE = 0.08838834764831845f;

    // Q fragments (B-operand: col=q=c16, k=d=ks*32+g*8+j)
    f16x8 qf[4];
    const f16* qbase = q + (size_t)qrow * QCOLS + h * HD;
#pragma unroll
    for (int ks = 0; ks < 4; ++ks) qf[ks] = *(const f16x8*)(qbase + ks * 32 + g * 8);

    f32x4 o[8] = {};
    float mrun = -INFINITY, lrun = 0.f;

    for (int ch = 0; ch <= qt; ++ch) {
        __syncthreads();
        {   // stage K chunk [64][128] swizzled
            const char* kg = (const char*)(k + (size_t)(ch * 64) * KCOLS + kvh * HD);
            int r = tid >> 2;
#pragma unroll
            for (int i = 0; i < 4; ++i) {
                int b = (tid & 3) * 16 + i * 64;
                uint4 d = *(const uint4*)(kg + (size_t)r * (KCOLS * 2) + b);
                *(uint4*)((char*)Ks + r * 256 + (b ^ ((r & 7) << 4))) = d;
            }
            // stage Vt chunk [128][64] swizzled
            const char* vg = (const char*)(vt + (size_t)(kvh * HD) * T_SEQ + ch * 64);
            int d2 = tid >> 1;
#pragma unroll
            for (int i = 0; i < 4; ++i) {
                int b = (tid & 1) * 16 + i * 32;
                uint4 dd = *(const uint4*)(vg + (size_t)d2 * (T_SEQ * 2) + b);
                *(uint4*)((char*)Vs + d2 * 128 + (b ^ ((d2 & 7) << 4))) = dd;
            }
        }
        __syncthreads();

        // S^T = K @ Q^T : 4 key-blocks x 4 d-slices
        f32x4 st[4];
#pragma unroll
        for (int kb = 0; kb < 4; ++kb) {
            f32x4 a = {};
#pragma unroll
            for (int ks = 0; ks < 4; ++ks) {
                int row = kb * 16 + c16;
                f16x8 kf = *(const f16x8*)((const char*)Ks + row * 256 +
                                           ((ks * 64 + g * 16) ^ ((row & 7) << 4)));
                a = __builtin_amdgcn_mfma_f32_16x16x32_f16(kf, qf[ks], a, 0, 0, 0);
            }
            st[kb] = a;
        }

        // scale + causal mask + online softmax (col q = c16 is lane-local)
        float p[16];
        float cmax = -INFINITY;
        const bool diag = (ch == qt);
#pragma unroll
        for (int kb = 0; kb < 4; ++kb)
#pragma unroll
            for (int r = 0; r < 4; ++r) {
                float s = st[kb][r] * SCALE;
                if (diag) {
                    int key = ch * 64 + kb * 16 + g * 4 + r;
                    if (key > qrow) s = -INFINITY;
                }
                p[kb * 4 + r] = s;
                cmax = fmaxf(cmax, s);
            }
        cmax = fmaxf(cmax, __shfl_xor(cmax, 16));
        cmax = fmaxf(cmax, __shfl_xor(cmax, 32));
        float mnew = fmaxf(mrun, cmax);
        float corr = __expf(mrun - mnew);
        float psum = 0.f;
#pragma unroll
        for (int i = 0; i < 16; ++i) { float e = __expf(p[i] - mnew); p[i] = e; psum += e; }
        psum += __shfl_xor(psum, 16);
        psum += __shfl_xor(psum, 32);
        lrun = lrun * corr + psum;
        mrun = mnew;
#pragma unroll
        for (int mb = 0; mb < 8; ++mb) o[mb] *= corr;

        // P -> per-wave LDS: row=q (c16), cols=keys, 4 consecutive keys per write
        f16* pw = Ps[w] + c16 * 72;
#pragma unroll
        for (int kb = 0; kb < 4; ++kb) {
            f16x4 q4 = {(f16)p[kb * 4], (f16)p[kb * 4 + 1], (f16)p[kb * 4 + 2], (f16)p[kb * 4 + 3]};
            *(f16x4*)(pw + kb * 16 + g * 4) = q4;
        }

        // O^T += Vt @ P^T : 8 d-blocks x 2 key-slices
#pragma unroll
        for (int ks2 = 0; ks2 < 2; ++ks2) {
            f16x8 pf = *(const f16x8*)(Ps[w] + c16 * 72 + ks2 * 32 + g * 8);
#pragma unroll
            for (int mb = 0; mb < 8; ++mb) {
                int row = mb * 16 + c16;
                f16x8 vf = *(const f16x8*)((const char*)Vs + row * 128 +
                                           ((ks2 * 64 + g * 16) ^ ((row & 7) << 4)));
                o[mb] = __builtin_amdgcn_mfma_f32_16x16x32_f16(vf, pf, o[mb], 0, 0, 0);
            }
        }
    }

    float invl = 1.f / lrun;
    f16* ob = outh + (size_t)qrow * QCOLS + h * HD;
#pragma unroll
    for (int mb = 0; mb < 8; ++mb) {
        f16x4 v = {(f16)(o[mb][0] * invl), (f16)(o[mb][1] * invl),
                   (f16)(o[mb][2] * invl), (f16)(o[mb][3] * invl)};
        *(f16x4*)(ob + mb * 16 + g * 4) = v;
    }
}

// ---------------- host launch ----------------
// Workspace plan (77 MB high-water; round-0 proved ws_size >= 81 MB):
//   [0,1)    cosT/sinT
//   [1,17)   xh   f16 [2048][4096]
//   [17,33)  qh   f16 [2048][4096]
//   [33,37)  kh   f16 [2048][1024]
//   [37,41)  vh   f16 [2048][1024]
//   [41,45)  vtb  f16 [1024][2048]
//   [45,61)  atth f16 [2048][4096]
//   [61,77)  wT   f16 scratch (weights transposed in <=2048-col slices, reused serially)
extern "C" void kernel_launch(void* const* d_in, const int* in_sizes, int n_in,
                              void* d_out, int out_size, void* d_ws, size_t ws_size,
                              hipStream_t stream) {
    const float* x  = (const float*)d_in[0];
    const float* wq = (const float*)d_in[1];
    const float* wk = (const float*)d_in[2];
    const float* wv = (const float*)d_in[3];
    const float* wo = (const float*)d_in[4];
    float* out = (float*)d_out;

    char* ws = (char*)d_ws;
    const size_t MB = 1024ULL * 1024ULL;
    float* cosT = (float*)(ws);
    float* sinT = (float*)(ws + 512 * 1024ULL);
    f16* xh   = (f16*)(ws + 1 * MB);
    f16* qh   = (f16*)(ws + 17 * MB);
    f16* kh   = (f16*)(ws + 33 * MB);
    f16* vh   = (f16*)(ws + 37 * MB);
    f16* vtb  = (f16*)(ws + 41 * MB);
    f16* atth = (f16*)(ws + 45 * MB);
    f16* wT   = (f16*)(ws + 61 * MB);

    rope_table<<<dim3((T_SEQ * 64 + 255) / 256), dim3(256), 0, stream>>>(cosT, sinT);
    convert_f32_f16<<<dim3(T_SEQ * HID / 8 / 256), dim3(256), 0, stream>>>(x, xh, T_SEQ * HID / 8);

    // Q = x @ wq, in two 2048-col halves through wT
    for (int half = 0; half < 2; ++half) {
        transpose_f32_to_f16<<<dim3(32, HID / 64), dim3(256), 0, stream>>>(
            wq + half * 2048, wT, HID, QCOLS);
        gemm_f16<f16><<<dim3(16, T_SEQ / 128), dim3(256), 0, stream>>>(
            xh, wT, qh + half * 2048, T_SEQ, QCOLS, HID);
    }
    // K = x @ wk
    transpose_f32_to_f16<<<dim3(KCOLS / 64, HID / 64), dim3(256), 0, stream>>>(wk, wT, HID, KCOLS);
    gemm_f16<f16><<<dim3(KCOLS / 128, T_SEQ / 128), dim3(256), 0, stream>>>(
        xh, wT, kh, T_SEQ, KCOLS, HID);
    // V = x @ wv
    transpose_f32_to_f16<<<dim3(KCOLS / 64, HID / 64), dim3(256), 0, stream>>>(wv, wT, HID, KCOLS);
    gemm_f16<f16><<<dim3(KCOLS / 128, T_SEQ / 128), dim3(256), 0, stream>>>(
        xh, wT, vh, T_SEQ, KCOLS, HID);

    rope_apply_f16<<<dim3(T_SEQ * NH * 64 / 256), dim3(256), 0, stream>>>(qh, cosT, sinT, NH);
    rope_apply_f16<<<dim3(T_SEQ * NKV * 64 / 256), dim3(256), 0, stream>>>(kh, cosT, sinT, NKV);

    transpose_f16<<<dim3(KCOLS / 64, T_SEQ / 64), dim3(256), 0, stream>>>(vh, vtb, T_SEQ, KCOLS);

    attn_f16<<<dim3(T_SEQ / 64, NH), dim3(256), 0, stream>>>(qh, kh, vtb, atth);

    // out = atth @ wo, in two 2048-col halves through wT
    for (int half = 0; half < 2; ++half) {
        transpose_f32_to_f16<<<dim3(32, QCOLS / 64), dim3(256), 0, stream>>>(
            wo + half * 2048, wT, QCOLS, HID);
        gemm_f16<float><<<dim3(16, T_SEQ / 128), dim3(256), 0, stream>>>(
            atth, wT, out + half * 2048, T_SEQ, HID, QCOLS);
    }
}

// Round 4
// 403.857 us; speedup vs baseline: 14.8568x; 1.8251x over previous
//
#include <hip/hip_runtime.h>
#include <math.h>

#define T_SEQ 2048
#define HID   4096
#define NH    32
#define NKV   8
#define HD    128
#define QCOLS (NH*HD)   // 4096
#define KCOLS (NKV*HD)  // 1024
#define KSTR  2048      // row stride of combined K|V buffer

typedef _Float16 f16;
typedef _Float16 f16x8 __attribute__((ext_vector_type(8)));
typedef _Float16 f16x4 __attribute__((ext_vector_type(4)));
typedef float f32x4 __attribute__((ext_vector_type(4)));

#define GLDS(g, l) __builtin_amdgcn_global_load_lds( \
    (const __attribute__((address_space(1))) void*)(g), \
    (__attribute__((address_space(3))) void*)(l), 16, 0, 0)

// ---------------- RoPE cos/sin table (llama3 scaling), f64 math ----------------
__global__ void rope_table(float* __restrict__ cosT, float* __restrict__ sinT) {
    int idx = blockIdx.x * blockDim.x + threadIdx.x;   // t*64 + i
    if (idx >= T_SEQ * 64) return;
    int t = idx >> 6, i = idx & 63;
    double inv = pow(500000.0, -(double)(2 * i) / 128.0);
    double wavelen = 6.283185307179586 / inv;
    const double lowwl = 8192.0, highwl = 2048.0;
    double scaled;
    if (wavelen > lowwl) {
        scaled = inv / 8.0;
    } else if (wavelen >= highwl) {
        double smooth = (8192.0 / wavelen - 1.0) / 3.0;
        scaled = (1.0 - smooth) * inv / 8.0 + smooth * inv;
    } else {
        scaled = inv;
    }
    float invf = (float)scaled;
    float phase = (float)t * invf;
    cosT[idx] = (float)cos((double)phase);
    sinT[idx] = (float)sin((double)phase);
}

// ---------------- fp32 -> f16 convert (row-major copy) ----------------
__global__ void convert_f32_f16(const float* __restrict__ in, f16* __restrict__ out, int n8) {
    int i = blockIdx.x * blockDim.x + threadIdx.x;
    if (i >= n8) return;
    float4 a = *(const float4*)(in + (size_t)i * 8);
    float4 b = *(const float4*)(in + (size_t)i * 8 + 4);
    f16x8 v = {(f16)a.x, (f16)a.y, (f16)a.z, (f16)a.w, (f16)b.x, (f16)b.y, (f16)b.z, (f16)b.w};
    *(f16x8*)(out + (size_t)i * 8) = v;
}

// ---------------- fp32 [rows][ld] col-slice -> f16 [cols][R] transpose ----------------
// grid.x covers slice cols/64, grid.y covers R/64 rows. out has row stride R.
__global__ __launch_bounds__(256) void transpose_f32_to_f16(const float* __restrict__ in,
                                                            f16* __restrict__ out,
                                                            int R, int ld) {
    __shared__ f16 t[64][72];
    const int tid = threadIdx.x;
    const int r0 = blockIdx.y * 64, c0 = blockIdx.x * 64;
#pragma unroll
    for (int i = 0; i < 4; ++i) {
        int r = i * 16 + (tid >> 4), c4 = (tid & 15) * 4;
        float4 v = *(const float4*)(in + (size_t)(r0 + r) * ld + c0 + c4);
        t[r][c4 + 0] = (f16)v.x; t[r][c4 + 1] = (f16)v.y;
        t[r][c4 + 2] = (f16)v.z; t[r][c4 + 3] = (f16)v.w;
    }
    __syncthreads();
    int n = tid >> 2, j0 = (tid & 3) * 16;
    f16x8 a, b;
#pragma unroll
    for (int j = 0; j < 8; ++j) { a[j] = t[j0 + j][n]; b[j] = t[j0 + 8 + j][n]; }
    *(f16x8*)(out + (size_t)(c0 + n) * R + r0 + j0) = a;
    *(f16x8*)(out + (size_t)(c0 + n) * R + r0 + j0 + 8) = b;
}

// ---------------- f16 [*][ld] 64x64-tiled transpose: out[(c0+n)*R + r] ----------------
__global__ __launch_bounds__(256) void transpose_f16(const f16* __restrict__ in,
                                                     f16* __restrict__ out,
                                                     int R, int ld) {
    __shared__ f16 t[64][72];
    const int tid = threadIdx.x;
    const int r0 = blockIdx.y * 64, c0 = blockIdx.x * 64;
#pragma unroll
    for (int i = 0; i < 2; ++i) {
        int r = i * 32 + (tid >> 3), c8 = (tid & 7) * 8;
        f16x8 v = *(const f16x8*)(in + (size_t)(r0 + r) * ld + c0 + c8);
#pragma unroll
        for (int j = 0; j < 8; ++j) t[r][c8 + j] = v[j];
    }
    __syncthreads();
    int n = tid >> 2, j0 = (tid & 3) * 16;
    f16x8 a, b;
#pragma unroll
    for (int j = 0; j < 8; ++j) { a[j] = t[j0 + j][n]; b[j] = t[j0 + 8 + j][n]; }
    *(f16x8*)(out + (size_t)(c0 + n) * R + r0 + j0) = a;
    *(f16x8*)(out + (size_t)(c0 + n) * R + r0 + j0 + 8) = b;
}

// ---------------- f16 MFMA GEMM: C[M, ldc] = A[M,K] @ Bt[N,K]^T ----------------
// 128x128 tile, BK=32, 256 threads (4 waves, 2x2), m97-style 2-barrier loop.
template <typename OutT>
__global__ __launch_bounds__(256, 2) void gemm_f16(const f16* __restrict__ A,
                                                   const f16* __restrict__ Bt,
                                                   OutT* __restrict__ C,
                                                   int M, int ldc, int K) {
    __shared__ f16 As[128 * 32];
    __shared__ f16 Bs[128 * 32];
    const int tid = threadIdx.x;
    const int l = tid & 63;
    const int w = tid >> 6, wr = w >> 1, wc = w & 1;
    const int c16 = l & 15, g = l >> 4;
    const int m0 = blockIdx.y * 128, n0 = blockIdx.x * 128;

    f32x4 acc[4][4] = {};

    const f16* gA = A + (size_t)(m0 + (tid >> 2)) * K + (tid & 3) * 8;
    const f16* gB = Bt + (size_t)(n0 + (tid >> 2)) * K + (tid & 3) * 8;
    f16* lA = As + tid * 8;
    f16* lB = Bs + tid * 8;

    for (int k0 = 0; k0 < K; k0 += 32) {
        __syncthreads();
        GLDS(gA + k0, lA);
        GLDS(gA + (size_t)64 * K + k0, lA + 64 * 32);
        GLDS(gB + k0, lB);
        GLDS(gB + (size_t)64 * K + k0, lB + 64 * 32);
        __syncthreads();
        f16x8 af[4], bf[4];
#pragma unroll
        for (int mb = 0; mb < 4; ++mb)
            af[mb] = *(const f16x8*)(As + (wr * 64 + mb * 16 + c16) * 32 + g * 8);
#pragma unroll
        for (int nb = 0; nb < 4; ++nb)
            bf[nb] = *(const f16x8*)(Bs + (wc * 64 + nb * 16 + c16) * 32 + g * 8);
#pragma unroll
        for (int mb = 0; mb < 4; ++mb)
#pragma unroll
            for (int nb = 0; nb < 4; ++nb)
                acc[mb][nb] = __builtin_amdgcn_mfma_f32_16x16x32_f16(af[mb], bf[nb], acc[mb][nb], 0, 0, 0);
    }
#pragma unroll
    for (int mb = 0; mb < 4; ++mb)
#pragma unroll
        for (int nb = 0; nb < 4; ++nb)
#pragma unroll
            for (int r = 0; r < 4; ++r) {
                size_t row = m0 + wr * 64 + mb * 16 + g * 4 + r;
                C[row * ldc + n0 + wc * 64 + nb * 16 + c16] = (OutT)acc[mb][nb][r];
            }
}

// ---------------- RoPE apply in place on f16 (row stride parameterized) ----------------
__global__ void rope_apply_f16(f16* __restrict__ data, const float* __restrict__ cosT,
                               const float* __restrict__ sinT, int nheads, int stride) {
    int idx = blockIdx.x * blockDim.x + threadIdx.x;
    int lane = idx & 63;
    int row = idx >> 6;
    if (row >= T_SEQ * nheads) return;
    int t = row / nheads, h = row % nheads;
    f16* p = data + (size_t)t * stride + h * HD;
    float c = cosT[t * 64 + lane], s = sinT[t * 64 + lane];
    float x1 = (float)p[lane], x2 = (float)p[lane + 64];
    p[lane]      = (f16)(x1 * c - x2 * s);
    p[lane + 64] = (f16)(x2 * c + x1 * s);
}

// ---------------- MFMA flash attention (swapped operands, balanced pairing) ----------------
// grid (16, NH); block bx handles qt = bx and qt = 31-bx (uniform 33 chunks).
// 256 threads = 4 waves; wave w owns q rows qt*64+w*16..+15.
// S^T = K @ Q^T (lane col = q, softmax state lane-local); O^T = Vt @ P^T.
__global__ __launch_bounds__(256, 3) void attn_f16(const f16* __restrict__ q,
                                                   const f16* __restrict__ k,
                                                   const f16* __restrict__ vt,
                                                   f16* __restrict__ outh) {
    __shared__ f16 Ks[64 * 128];   // rows of 256 B, XOR-swizzled
    __shared__ f16 Vs[128 * 64];   // Vt rows of 128 B, XOR-swizzled
    __shared__ f16 Ps[4][16 * 72]; // per-wave P, row stride 72 f16
    const int tid = threadIdx.x;
    const int l = tid & 63, w = tid >> 6;
    const int c16 = l & 15, g = l >> 4;
    const int h = blockIdx.y, kvh = h >> 2;
    const float SCALE = 0.08838834764831845f;

    for (int pass = 0; pass < 2; ++pass) {
        const int qt = pass ? 31 - (int)blockIdx.x : (int)blockIdx.x;
        const int qrow = qt * 64 + w * 16 + c16;

        f16x8 qf[4];
        const f16* qbase = q + (size_t)qrow * QCOLS + h * HD;
#pragma unroll
        for (int ks = 0; ks < 4; ++ks) qf[ks] = *(const f16x8*)(qbase + ks * 32 + g * 8);

        f32x4 o[8] = {};
        float mrun = -INFINITY, lrun = 0.f;

        for (int ch = 0; ch <= qt; ++ch) {
            __syncthreads();
            {   // stage K chunk [64][128] swizzled (K row stride KSTR)
                const char* kg = (const char*)(k + (size_t)(ch * 64) * KSTR + kvh * HD);
                int r = tid >> 2;
#pragma unroll
                for (int i = 0; i < 4; ++i) {
                    int b = (tid & 3) * 16 + i * 64;
                    uint4 d = *(const uint4*)(kg + (size_t)r * (KSTR * 2) + b);
                    *(uint4*)((char*)Ks + r * 256 + (b ^ ((r & 7) << 4))) = d;
                }
                // stage Vt chunk [128][64] swizzled (Vt row stride T_SEQ)
                const char* vg = (const char*)(vt + (size_t)(kvh * HD) * T_SEQ + ch * 64);
                int d2 = tid >> 1;
#pragma unroll
                for (int i = 0; i < 4; ++i) {
                    int b = (tid & 1) * 16 + i * 32;
                    uint4 dd = *(const uint4*)(vg + (size_t)d2 * (T_SEQ * 2) + b);
                    *(uint4*)((char*)Vs + d2 * 128 + (b ^ ((d2 & 7) << 4))) = dd;
                }
            }
            __syncthreads();

            // S^T = K @ Q^T : 4 key-blocks x 4 d-slices
            f32x4 st[4];
            __builtin_amdgcn_s_setprio(1);
#pragma unroll
            for (int kb = 0; kb < 4; ++kb) {
                f32x4 a = {};
#pragma unroll
                for (int ks = 0; ks < 4; ++ks) {
                    int row = kb * 16 + c16;
                    f16x8 kf = *(const f16x8*)((const char*)Ks + row * 256 +
                                               ((ks * 64 + g * 16) ^ ((row & 7) << 4)));
                    a = __builtin_amdgcn_mfma_f32_16x16x32_f16(kf, qf[ks], a, 0, 0, 0);
                }
                st[kb] = a;
            }
            __builtin_amdgcn_s_setprio(0);

            // scale + causal mask + online softmax (col q = c16 is lane-local)
            float p[16];
            float cmax = -INFINITY;
            const bool diag = (ch == qt);
#pragma unroll
            for (int kb = 0; kb < 4; ++kb)
#pragma unroll
                for (int r = 0; r < 4; ++r) {
                    float s = st[kb][r] * SCALE;
                    if (diag) {
                        int key = ch * 64 + kb * 16 + g * 4 + r;
                        if (key > qrow) s = -INFINITY;
                    }
                    p[kb * 4 + r] = s;
                    cmax = fmaxf(cmax, s);
                }
            cmax = fmaxf(cmax, __shfl_xor(cmax, 16));
            cmax = fmaxf(cmax, __shfl_xor(cmax, 32));
            float mnew = fmaxf(mrun, cmax);
            float corr = __expf(mrun - mnew);
            float psum = 0.f;
#pragma unroll
            for (int i = 0; i < 16; ++i) { float e = __expf(p[i] - mnew); p[i] = e; psum += e; }
            psum += __shfl_xor(psum, 16);
            psum += __shfl_xor(psum, 32);
            lrun = lrun * corr + psum;
            mrun = mnew;
#pragma unroll
            for (int mb = 0; mb < 8; ++mb) o[mb] *= corr;

            // P -> per-wave LDS: row=q (c16), cols=keys
            f16* pw = Ps[w] + c16 * 72;
#pragma unroll
            for (int kb = 0; kb < 4; ++kb) {
                f16x4 q4 = {(f16)p[kb * 4], (f16)p[kb * 4 + 1], (f16)p[kb * 4 + 2], (f16)p[kb * 4 + 3]};
                *(f16x4*)(pw + kb * 16 + g * 4) = q4;
            }

            // O^T += Vt @ P^T : 8 d-blocks x 2 key-slices
            __builtin_amdgcn_s_setprio(1);
#pragma unroll
            for (int ks2 = 0; ks2 < 2; ++ks2) {
                f16x8 pf = *(const f16x8*)(Ps[w] + c16 * 72 + ks2 * 32 + g * 8);
#pragma unroll
                for (int mb = 0; mb < 8; ++mb) {
                    int row = mb * 16 + c16;
                    f16x8 vf = *(const f16x8*)((const char*)Vs + row * 128 +
                                               ((ks2 * 64 + g * 16) ^ ((row & 7) << 4)));
                    o[mb] = __builtin_amdgcn_mfma_f32_16x16x32_f16(vf, pf, o[mb], 0, 0, 0);
                }
            }
            __builtin_amdgcn_s_setprio(0);
        }

        float invl = 1.f / lrun;
        f16* ob = outh + (size_t)qrow * QCOLS + h * HD;
#pragma unroll
        for (int mb = 0; mb < 8; ++mb) {
            f16x4 v = {(f16)(o[mb][0] * invl), (f16)(o[mb][1] * invl),
                       (f16)(o[mb][2] * invl), (f16)(o[mb][3] * invl)};
            *(f16x4*)(ob + mb * 16 + g * 4) = v;
        }
    }
}

// ---------------- host launch ----------------
// Workspace (77 MB high-water; round-0 proved ws_size >= 83 MB):
//   [0,1)    cosT/sinT
//   [1,17)   xh f16 [2048][4096]; aliased by atth after QKV GEMMs
//   [17,33)  qh f16 [2048][4096]
//   [33,41)  kvh f16 [2048][2048]  (K cols 0..1023 | V cols 1024..2047)
//   [41,73)  wT f16 scratch (wqT 32MB -> wkT|wvT 16MB -> woT 32MB, serial reuse)
//   [73,77)  vtb f16 [1024][2048]
extern "C" void kernel_launch(void* const* d_in, const int* in_sizes, int n_in,
                              void* d_out, int out_size, void* d_ws, size_t ws_size,
                              hipStream_t stream) {
    const float* x  = (const float*)d_in[0];
    const float* wq = (const float*)d_in[1];
    const float* wk = (const float*)d_in[2];
    const float* wv = (const float*)d_in[3];
    const float* wo = (const float*)d_in[4];
    float* out = (float*)d_out;

    char* ws = (char*)d_ws;
    const size_t MB = 1024ULL * 1024ULL;
    float* cosT = (float*)(ws);
    float* sinT = (float*)(ws + 512 * 1024ULL);
    f16* xh   = (f16*)(ws + 1 * MB);
    f16* atth = xh;  // alias: xh dead after QKV GEMMs
    f16* qh   = (f16*)(ws + 17 * MB);
    f16* kvh  = (f16*)(ws + 33 * MB);
    f16* wT   = (f16*)(ws + 41 * MB);
    f16* vtb  = (f16*)(ws + 73 * MB);

    rope_table<<<dim3((T_SEQ * 64 + 255) / 256), dim3(256), 0, stream>>>(cosT, sinT);
    convert_f32_f16<<<dim3(T_SEQ * HID / 8 / 256), dim3(256), 0, stream>>>(x, xh, T_SEQ * HID / 8);

    // Q = x @ wq  (one 512-block launch)
    transpose_f32_to_f16<<<dim3(QCOLS / 64, HID / 64), dim3(256), 0, stream>>>(wq, wT, HID, QCOLS);
    gemm_f16<f16><<<dim3(QCOLS / 128, T_SEQ / 128), dim3(256), 0, stream>>>(
        xh, wT, qh, T_SEQ, QCOLS, HID);

    // K|V = x @ [wk|wv]  (one 256-block launch into kvh[2048][2048])
    transpose_f32_to_f16<<<dim3(KCOLS / 64, HID / 64), dim3(256), 0, stream>>>(wk, wT, HID, KCOLS);
    transpose_f32_to_f16<<<dim3(KCOLS / 64, HID / 64), dim3(256), 0, stream>>>(
        wv, wT + (size_t)KCOLS * HID, HID, KCOLS);
    gemm_f16<f16><<<dim3(KSTR / 128, T_SEQ / 128), dim3(256), 0, stream>>>(
        xh, wT, kvh, T_SEQ, KSTR, HID);

    rope_apply_f16<<<dim3(T_SEQ * NH * 64 / 256), dim3(256), 0, stream>>>(
        qh, cosT, sinT, NH, QCOLS);
    rope_apply_f16<<<dim3(T_SEQ * NKV * 64 / 256), dim3(256), 0, stream>>>(
        kvh, cosT, sinT, NKV, KSTR);

    // vtb[d][t] = V^T from kvh cols 1024..2047
    transpose_f16<<<dim3(KCOLS / 64, T_SEQ / 64), dim3(256), 0, stream>>>(
        kvh + KCOLS, vtb, T_SEQ, KSTR);

    attn_f16<<<dim3(16, NH), dim3(256), 0, stream>>>(qh, kvh, vtb, atth);

    // out = atth @ wo  (one 512-block launch)
    transpose_f32_to_f16<<<dim3(HID / 64, QCOLS / 64), dim3(256), 0, stream>>>(wo, wT, QCOLS, HID);
    gemm_f16<float><<<dim3(HID / 128, T_SEQ / 128), dim3(256), 0, stream>>>(
        atth, wT, out, T_SEQ, HID, QCOLS);
}

// Round 5
// 363.379 us; speedup vs baseline: 16.5118x; 1.1114x over previous
//
#include <hip/hip_runtime.h>
#include <math.h>

#define T_SEQ 2048
#define HID   4096
#define NH    32
#define NKV   8
#define HD    128
#define QCOLS (NH*HD)   // 4096
#define KCOLS (NKV*HD)  // 1024
#define KSTR  2048      // row stride of combined K|V buffer

typedef _Float16 f16;
typedef _Float16 f16x8 __attribute__((ext_vector_type(8)));
typedef _Float16 f16x4 __attribute__((ext_vector_type(4)));
typedef float f32x4 __attribute__((ext_vector_type(4)));

#define GLDS(g, l) __builtin_amdgcn_global_load_lds( \
    (const __attribute__((address_space(1))) void*)(g), \
    (__attribute__((address_space(3))) void*)(l), 16, 0, 0)

// ---------------- RoPE cos/sin table (llama3 scaling), f64 math ----------------
__global__ void rope_table(float* __restrict__ cosT, float* __restrict__ sinT) {
    int idx = blockIdx.x * blockDim.x + threadIdx.x;   // t*64 + i
    if (idx >= T_SEQ * 64) return;
    int t = idx >> 6, i = idx & 63;
    double inv = pow(500000.0, -(double)(2 * i) / 128.0);
    double wavelen = 6.283185307179586 / inv;
    const double lowwl = 8192.0, highwl = 2048.0;
    double scaled;
    if (wavelen > lowwl) {
        scaled = inv / 8.0;
    } else if (wavelen >= highwl) {
        double smooth = (8192.0 / wavelen - 1.0) / 3.0;
        scaled = (1.0 - smooth) * inv / 8.0 + smooth * inv;
    } else {
        scaled = inv;
    }
    float invf = (float)scaled;
    float phase = (float)t * invf;
    cosT[idx] = (float)cos((double)phase);
    sinT[idx] = (float)sin((double)phase);
}

// ---------------- fp32 -> f16 convert (row-major copy) ----------------
__global__ void convert_f32_f16(const float* __restrict__ in, f16* __restrict__ out, int n8) {
    int i = blockIdx.x * blockDim.x + threadIdx.x;
    if (i >= n8) return;
    float4 a = *(const float4*)(in + (size_t)i * 8);
    float4 b = *(const float4*)(in + (size_t)i * 8 + 4);
    f16x8 v = {(f16)a.x, (f16)a.y, (f16)a.z, (f16)a.w, (f16)b.x, (f16)b.y, (f16)b.z, (f16)b.w};
    *(f16x8*)(out + (size_t)i * 8) = v;
}

// ---------------- fp32 [rows][ld] col-slice -> f16 [cols][R] transpose ----------------
__global__ __launch_bounds__(256) void transpose_f32_to_f16(const float* __restrict__ in,
                                                            f16* __restrict__ out,
                                                            int R, int ld) {
    __shared__ f16 t[64][72];
    const int tid = threadIdx.x;
    const int r0 = blockIdx.y * 64, c0 = blockIdx.x * 64;
#pragma unroll
    for (int i = 0; i < 4; ++i) {
        int r = i * 16 + (tid >> 4), c4 = (tid & 15) * 4;
        float4 v = *(const float4*)(in + (size_t)(r0 + r) * ld + c0 + c4);
        t[r][c4 + 0] = (f16)v.x; t[r][c4 + 1] = (f16)v.y;
        t[r][c4 + 2] = (f16)v.z; t[r][c4 + 3] = (f16)v.w;
    }
    __syncthreads();
    int n = tid >> 2, j0 = (tid & 3) * 16;
    f16x8 a, b;
#pragma unroll
    for (int j = 0; j < 8; ++j) { a[j] = t[j0 + j][n]; b[j] = t[j0 + 8 + j][n]; }
    *(f16x8*)(out + (size_t)(c0 + n) * R + r0 + j0) = a;
    *(f16x8*)(out + (size_t)(c0 + n) * R + r0 + j0 + 8) = b;
}

// ---------------- f16 [*][ld] 64x64-tiled transpose ----------------
__global__ __launch_bounds__(256) void transpose_f16(const f16* __restrict__ in,
                                                     f16* __restrict__ out,
                                                     int R, int ld) {
    __shared__ f16 t[64][72];
    const int tid = threadIdx.x;
    const int r0 = blockIdx.y * 64, c0 = blockIdx.x * 64;
#pragma unroll
    for (int i = 0; i < 2; ++i) {
        int r = i * 32 + (tid >> 3), c8 = (tid & 7) * 8;
        f16x8 v = *(const f16x8*)(in + (size_t)(r0 + r) * ld + c0 + c8);
#pragma unroll
        for (int j = 0; j < 8; ++j) t[r][c8 + j] = v[j];
    }
    __syncthreads();
    int n = tid >> 2, j0 = (tid & 3) * 16;
    f16x8 a, b;
#pragma unroll
    for (int j = 0; j < 8; ++j) { a[j] = t[j0 + j][n]; b[j] = t[j0 + 8 + j][n]; }
    *(f16x8*)(out + (size_t)(c0 + n) * R + r0 + j0) = a;
    *(f16x8*)(out + (size_t)(c0 + n) * R + r0 + j0 + 8) = b;
}

// ---------------- f16 MFMA GEMM: C[M, ldc] = A[M,K] @ Bt[N,K]^T ----------------
// 128x128 tile, BK=64, double-buffered LDS, ONE barrier per K-step.
// Prefetch of tile t+1 issues before compute of tile t (T3 minimum 2-phase).
// LDS rows are 128 B -> XOR-swizzle (row&7)<<4 applied via pre-swizzled global
// source (linear GLDS dest, rule #21) and on the fragment ds_read side.
template <typename OutT>
__global__ __launch_bounds__(256, 2) void gemm_f16(const f16* __restrict__ A,
                                                   const f16* __restrict__ Bt,
                                                   OutT* __restrict__ C,
                                                   int M, int ldc, int K) {
    __shared__ f16 As[2][128 * 64];
    __shared__ f16 Bs[2][128 * 64];
    const int tid = threadIdx.x;
    const int l = tid & 63;
    const int w = tid >> 6, wr = w >> 1, wc = w & 1;
    const int c16 = l & 15, g = l >> 4;
    const int m0 = blockIdx.y * 128, n0 = blockIdx.x * 128;

    f32x4 acc[4][4] = {};

    // staging: 4 issues per matrix; issue i covers rows i*32 + tid/8, 16B slot tid&7.
    // source column pre-swizzled so LDS content at byte p equals global byte p^((row&7)<<4).
    const int r_src = tid >> 3;                               // 0..31 (row mod 32)
    const int colswz = ((tid & 7) * 8) ^ ((r_src & 7) << 3);  // f16 units within BK=64
    const f16* gA = A + (size_t)(m0 + r_src) * K + colswz;
    const f16* gB = Bt + (size_t)(n0 + r_src) * K + colswz;

    auto stage = [&](f16* sA, f16* sB, int k0) {
#pragma unroll
        for (int i = 0; i < 4; ++i) {
            GLDS(gA + (size_t)(i * 32) * K + k0, sA + i * 2048 + tid * 8);
            GLDS(gB + (size_t)(i * 32) * K + k0, sB + i * 2048 + tid * 8);
        }
    };
    auto compute = [&](const f16* sA, const f16* sB) {
#pragma unroll
        for (int kk = 0; kk < 2; ++kk) {
            f16x8 af[4], bf[4];
#pragma unroll
            for (int mb = 0; mb < 4; ++mb) {
                int row = wr * 64 + mb * 16 + c16;
                af[mb] = *(const f16x8*)((const char*)sA + row * 128 +
                                         ((kk * 64 + g * 16) ^ ((row & 7) << 4)));
            }
#pragma unroll
            for (int nb = 0; nb < 4; ++nb) {
                int row = wc * 64 + nb * 16 + c16;
                bf[nb] = *(const f16x8*)((const char*)sB + row * 128 +
                                         ((kk * 64 + g * 16) ^ ((row & 7) << 4)));
            }
#pragma unroll
            for (int mb = 0; mb < 4; ++mb)
#pragma unroll
                for (int nb = 0; nb < 4; ++nb)
                    acc[mb][nb] = __builtin_amdgcn_mfma_f32_16x16x32_f16(af[mb], bf[nb], acc[mb][nb], 0, 0, 0);
        }
    };

    stage(As[0], Bs[0], 0);
    __syncthreads();
    int cur = 0;
    for (int k0 = 64; k0 < K; k0 += 64) {
        stage(As[cur ^ 1], Bs[cur ^ 1], k0);   // prefetch next tile (in flight across compute)
        compute(As[cur], Bs[cur]);
        __syncthreads();                       // drains prefetch; all waves done with cur
        cur ^= 1;
    }
    compute(As[cur], Bs[cur]);

#pragma unroll
    for (int mb = 0; mb < 4; ++mb)
#pragma unroll
        for (int nb = 0; nb < 4; ++nb)
#pragma unroll
            for (int r = 0; r < 4; ++r) {
                size_t row = m0 + wr * 64 + mb * 16 + g * 4 + r;
                C[row * ldc + n0 + wc * 64 + nb * 16 + c16] = (OutT)acc[mb][nb][r];
            }
}

// ---------------- RoPE apply in place on f16 (row stride parameterized) ----------------
__global__ void rope_apply_f16(f16* __restrict__ data, const float* __restrict__ cosT,
                               const float* __restrict__ sinT, int nheads, int stride) {
    int idx = blockIdx.x * blockDim.x + threadIdx.x;
    int lane = idx & 63;
    int row = idx >> 6;
    if (row >= T_SEQ * nheads) return;
    int t = row / nheads, h = row % nheads;
    f16* p = data + (size_t)t * stride + h * HD;
    float c = cosT[t * 64 + lane], s = sinT[t * 64 + lane];
    float x1 = (float)p[lane], x2 = (float)p[lane + 64];
    p[lane]      = (f16)(x1 * c - x2 * s);
    p[lane + 64] = (f16)(x2 * c + x1 * s);
}

// ---------------- MFMA flash attention (swapped operands, balanced pairing) ----------------
__global__ __launch_bounds__(256, 3) void attn_f16(const f16* __restrict__ q,
                                                   const f16* __restrict__ k,
                                                   const f16* __restrict__ vt,
                                                   f16* __restrict__ outh) {
    __shared__ f16 Ks[64 * 128];   // rows of 256 B, XOR-swizzled
    __shared__ f16 Vs[128 * 64];   // Vt rows of 128 B, XOR-swizzled
    __shared__ f16 Ps[4][16 * 72]; // per-wave P, row stride 72 f16
    const int tid = threadIdx.x;
    const int l = tid & 63, w = tid >> 6;
    const int c16 = l & 15, g = l >> 4;
    const int h = blockIdx.y, kvh = h >> 2;
    const float SCALE = 0.08838834764831845f;

    for (int pass = 0; pass < 2; ++pass) {
        const int qt = pass ? 31 - (int)blockIdx.x : (int)blockIdx.x;
        const int qrow = qt * 64 + w * 16 + c16;

        f16x8 qf[4];
        const f16* qbase = q + (size_t)qrow * QCOLS + h * HD;
#pragma unroll
        for (int ks = 0; ks < 4; ++ks) qf[ks] = *(const f16x8*)(qbase + ks * 32 + g * 8);

        f32x4 o[8] = {};
        float mrun = -INFINITY, lrun = 0.f;

        for (int ch = 0; ch <= qt; ++ch) {
            __syncthreads();
            {   // stage K chunk [64][128] swizzled (K row stride KSTR)
                const char* kg = (const char*)(k + (size_t)(ch * 64) * KSTR + kvh * HD);
                int r = tid >> 2;
#pragma unroll
                for (int i = 0; i < 4; ++i) {
                    int b = (tid & 3) * 16 + i * 64;
                    uint4 d = *(const uint4*)(kg + (size_t)r * (KSTR * 2) + b);
                    *(uint4*)((char*)Ks + r * 256 + (b ^ ((r & 7) << 4))) = d;
                }
                // stage Vt chunk [128][64] swizzled (Vt row stride T_SEQ)
                const char* vg = (const char*)(vt + (size_t)(kvh * HD) * T_SEQ + ch * 64);
                int d2 = tid >> 1;
#pragma unroll
                for (int i = 0; i < 4; ++i) {
                    int b = (tid & 1) * 16 + i * 32;
                    uint4 dd = *(const uint4*)(vg + (size_t)d2 * (T_SEQ * 2) + b);
                    *(uint4*)((char*)Vs + d2 * 128 + (b ^ ((d2 & 7) << 4))) = dd;
                }
            }
            __syncthreads();

            // S^T = K @ Q^T : 4 key-blocks x 4 d-slices
            f32x4 st[4];
            __builtin_amdgcn_s_setprio(1);
#pragma unroll
            for (int kb = 0; kb < 4; ++kb) {
                f32x4 a = {};
#pragma unroll
                for (int ks = 0; ks < 4; ++ks) {
                    int row = kb * 16 + c16;
                    f16x8 kf = *(const f16x8*)((const char*)Ks + row * 256 +
                                               ((ks * 64 + g * 16) ^ ((row & 7) << 4)));
                    a = __builtin_amdgcn_mfma_f32_16x16x32_f16(kf, qf[ks], a, 0, 0, 0);
                }
                st[kb] = a;
            }
            __builtin_amdgcn_s_setprio(0);

            // scale + causal mask + online softmax (col q = c16 is lane-local)
            float p[16];
            float cmax = -INFINITY;
            const bool diag = (ch == qt);
#pragma unroll
            for (int kb = 0; kb < 4; ++kb)
#pragma unroll
                for (int r = 0; r < 4; ++r) {
                    float s = st[kb][r] * SCALE;
                    if (diag) {
                        int key = ch * 64 + kb * 16 + g * 4 + r;
                        if (key > qrow) s = -INFINITY;
                    }
                    p[kb * 4 + r] = s;
                    cmax = fmaxf(cmax, s);
                }
            cmax = fmaxf(cmax, __shfl_xor(cmax, 16));
            cmax = fmaxf(cmax, __shfl_xor(cmax, 32));
            float mnew = fmaxf(mrun, cmax);
            float corr = __expf(mrun - mnew);
            float psum = 0.f;
#pragma unroll
            for (int i = 0; i < 16; ++i) { float e = __expf(p[i] - mnew); p[i] = e; psum += e; }
            psum += __shfl_xor(psum, 16);
            psum += __shfl_xor(psum, 32);
            lrun = lrun * corr + psum;
            mrun = mnew;
#pragma unroll
            for (int mb = 0; mb < 8; ++mb) o[mb] *= corr;

            // P -> per-wave LDS: row=q (c16), cols=keys
            f16* pw = Ps[w] + c16 * 72;
#pragma unroll
            for (int kb = 0; kb < 4; ++kb) {
                f16x4 q4 = {(f16)p[kb * 4], (f16)p[kb * 4 + 1], (f16)p[kb * 4 + 2], (f16)p[kb * 4 + 3]};
                *(f16x4*)(pw + kb * 16 + g * 4) = q4;
            }

            // O^T += Vt @ P^T : 8 d-blocks x 2 key-slices
            __builtin_amdgcn_s_setprio(1);
#pragma unroll
            for (int ks2 = 0; ks2 < 2; ++ks2) {
                f16x8 pf = *(const f16x8*)(Ps[w] + c16 * 72 + ks2 * 32 + g * 8);
#pragma unroll
                for (int mb = 0; mb < 8; ++mb) {
                    int row = mb * 16 + c16;
                    f16x8 vf = *(const f16x8*)((const char*)Vs + row * 128 +
                                               ((ks2 * 64 + g * 16) ^ ((row & 7) << 4)));
                    o[mb] = __builtin_amdgcn_mfma_f32_16x16x32_f16(vf, pf, o[mb], 0, 0, 0);
                }
            }
            __builtin_amdgcn_s_setprio(0);
        }

        float invl = 1.f / lrun;
        f16* ob = outh + (size_t)qrow * QCOLS + h * HD;
#pragma unroll
        for (int mb = 0; mb < 8; ++mb) {
            f16x4 v = {(f16)(o[mb][0] * invl), (f16)(o[mb][1] * invl),
                       (f16)(o[mb][2] * invl), (f16)(o[mb][3] * invl)};
            *(f16x4*)(ob + mb * 16 + g * 4) = v;
        }
    }
}

// ---------------- host launch ----------------
// Workspace (77 MB high-water; round-0 proved ws_size >= 81 MB):
//   [0,1) cos/sin  [1,17) xh (->atth)  [17,33) qh  [33,41) kvh  [41,73) wT  [73,77) vtb
extern "C" void kernel_launch(void* const* d_in, const int* in_sizes, int n_in,
                              void* d_out, int out_size, void* d_ws, size_t ws_size,
                              hipStream_t stream) {
    const float* x  = (const float*)d_in[0];
    const float* wq = (const float*)d_in[1];
    const float* wk = (const float*)d_in[2];
    const float* wv = (const float*)d_in[3];
    const float* wo = (const float*)d_in[4];
    float* out = (float*)d_out;

    char* ws = (char*)d_ws;
    const size_t MB = 1024ULL * 1024ULL;
    float* cosT = (float*)(ws);
    float* sinT = (float*)(ws + 512 * 1024ULL);
    f16* xh   = (f16*)(ws + 1 * MB);
    f16* atth = xh;  // alias: xh dead after QKV GEMMs
    f16* qh   = (f16*)(ws + 17 * MB);
    f16* kvh  = (f16*)(ws + 33 * MB);
    f16* wT   = (f16*)(ws + 41 * MB);
    f16* vtb  = (f16*)(ws + 73 * MB);

    rope_table<<<dim3((T_SEQ * 64 + 255) / 256), dim3(256), 0, stream>>>(cosT, sinT);
    convert_f32_f16<<<dim3(T_SEQ * HID / 8 / 256), dim3(256), 0, stream>>>(x, xh, T_SEQ * HID / 8);

    // Q = x @ wq
    transpose_f32_to_f16<<<dim3(QCOLS / 64, HID / 64), dim3(256), 0, stream>>>(wq, wT, HID, QCOLS);
    gemm_f16<f16><<<dim3(QCOLS / 128, T_SEQ / 128), dim3(256), 0, stream>>>(
        xh, wT, qh, T_SEQ, QCOLS, HID);

    // K|V = x @ [wk|wv] into kvh[2048][2048]
    transpose_f32_to_f16<<<dim3(KCOLS / 64, HID / 64), dim3(256), 0, stream>>>(wk, wT, HID, KCOLS);
    transpose_f32_to_f16<<<dim3(KCOLS / 64, HID / 64), dim3(256), 0, stream>>>(
        wv, wT + (size_t)KCOLS * HID, HID, KCOLS);
    gemm_f16<f16><<<dim3(KSTR / 128, T_SEQ / 128), dim3(256), 0, stream>>>(
        xh, wT, kvh, T_SEQ, KSTR, HID);

    rope_apply_f16<<<dim3(T_SEQ * NH * 64 / 256), dim3(256), 0, stream>>>(
        qh, cosT, sinT, NH, QCOLS);
    rope_apply_f16<<<dim3(T_SEQ * NKV * 64 / 256), dim3(256), 0, stream>>>(
        kvh, cosT, sinT, NKV, KSTR);

    // vtb[d][t] = V^T from kvh cols 1024..2047
    transpose_f16<<<dim3(KCOLS / 64, T_SEQ / 64), dim3(256), 0, stream>>>(
        kvh + KCOLS, vtb, T_SEQ, KSTR);

    attn_f16<<<dim3(16, NH), dim3(256), 0, stream>>>(qh, kvh, vtb, atth);

    // out = atth @ wo
    transpose_f32_to_f16<<<dim3(HID / 64, QCOLS / 64), dim3(256), 0, stream>>>(wo, wT, QCOLS, HID);
    gemm_f16<float><<<dim3(HID / 128, T_SEQ / 128), dim3(256), 0, stream>>>(
        atth, wT, out, T_SEQ, HID, QCOLS);
}